// Round 8
// baseline (791.498 us; speedup 1.0000x reference)
//
#include <hip/hip_runtime.h>
#include <hip/hip_bf16.h>
#include <math.h>

// SpatialGNN: B=64, N=1024 (32x32 grid), D_FEAT=1024, CTX=512, S=32, T=4
#define NB 64
#define NNODES 1024
#define CTXD 512
#define SEQL 32

typedef __attribute__((ext_vector_type(8))) short short8;
typedef __attribute__((ext_vector_type(4))) float floatx4;

__device__ __forceinline__ float bf2f(unsigned short u) {
  union { unsigned int i; float f; } v; v.i = ((unsigned int)u) << 16; return v.f;
}
__device__ __forceinline__ unsigned short f2bf(float f) {
  union { float f; unsigned int i; } v; v.f = f;
  unsigned int r = v.i + 0x7fffu + ((v.i >> 16) & 1u);  // RNE
  return (unsigned short)(r >> 16);
}
__device__ __forceinline__ float elu1(float x) { return x > 0.f ? x : expm1f(x); }

// ---------------------------------------------------------------------------
// Pack: bf16 GEMM weights + f32 TRANSPOSED cmd-path weights (coalesced GEMV).
// ---------------------------------------------------------------------------
__global__ __launch_bounds__(256) void pack_k(const float* __restrict__ kbw,
                                              const float* __restrict__ Ww,
                                              const float* __restrict__ qiw,
                                              const float* __restrict__ qtw,
                                              unsigned short* __restrict__ kb_bf,
                                              unsigned short* __restrict__ w1_bf,
                                              float* __restrict__ qiT,
                                              float* __restrict__ qTT,
                                              float* __restrict__ w2T) {
  int idx = blockIdx.x * 256 + threadIdx.x;
  if (idx < 524288) {
    kb_bf[idx] = f2bf(kbw[idx]);
  } else if (idx < 786432) {
    int o = idx - 524288;
    w1_bf[o] = f2bf(Ww[(o >> 9) * 1024 + (o & 511)]);
  } else if (idx < 1048576) {
    int o = idx - 786432;
    int k = o >> 9, c = o & 511;
    qiT[o] = qiw[c * 512 + k];
  } else if (idx < 2097152) {
    int o = idx - 1048576;
    int t = o >> 18, r = o & 262143;
    int k = r >> 9, c = r & 511;
    qTT[o] = qtw[((size_t)t * 512 + c) * 512 + k];
  } else {
    int o = idx - 2097152;
    int k = o >> 9, c = o & 511;
    w2T[o] = Ww[c * 1024 + 512 + k];
  }
}

// ---------------------------------------------------------------------------
// q1[b][c] = elu(q_enc[b] @ qInput_w^T + qInput_b)
// ---------------------------------------------------------------------------
__global__ __launch_bounds__(512) void q1_k(const float* __restrict__ q_enc,
                                            const float* __restrict__ qiT,
                                            const float* __restrict__ qInput_b,
                                            float* __restrict__ q1) {
  int b = blockIdx.x, c = threadIdx.x;
  __shared__ float qes[512];
  qes[c] = q_enc[b * 512 + c];
  __syncthreads();
  float a0 = qInput_b[c], a1 = 0.f, a2 = 0.f, a3 = 0.f;
#pragma unroll 4
  for (int k = 0; k < 512; k += 4) {
    a0 += qes[k] * qiT[k * 512 + c];
    a1 += qes[k + 1] * qiT[(k + 1) * 512 + c];
    a2 += qes[k + 2] * qiT[(k + 2) * 512 + c];
    a3 += qes[k + 3] * qiT[(k + 3) * 512 + c];
  }
  q1[b * 512 + c] = elu1(a0 + a1 + a2 + a3);
}

// ---------------------------------------------------------------------------
// Per (t,b): q_cmd -> raw_att -> softmax -> cmd -> bias2[t][b][:]
// ---------------------------------------------------------------------------
__global__ __launch_bounds__(512) void cmdt_k(
    const float* __restrict__ q1, const float* __restrict__ lstm,
    const int* __restrict__ q_len,
    const float* __restrict__ qTT, const float* __restrict__ qT_b,
    const float* __restrict__ cmd_w, const float* __restrict__ cmd_b,
    const float* __restrict__ w2T, const float* __restrict__ W_b,
    float* __restrict__ bias2) {
  int b = blockIdx.x & 63;
  int t = blockIdx.x >> 6;
  int c = threadIdx.x;
  __shared__ float q1s[512];
  __shared__ float us[512];
  __shared__ float red[512];
  __shared__ float atts[32];
  __shared__ float cmds[512];

  q1s[c] = q1[b * 512 + c];
  __syncthreads();

  const float* wt = qTT + (size_t)t * 262144;
  float a0 = qT_b[t * 512 + c], a1 = 0.f, a2 = 0.f, a3 = 0.f;
#pragma unroll 4
  for (int k = 0; k < 512; k += 4) {
    a0 += q1s[k] * wt[k * 512 + c];
    a1 += q1s[k + 1] * wt[(k + 1) * 512 + c];
    a2 += q1s[k + 2] * wt[(k + 2) * 512 + c];
    a3 += q1s[k + 3] * wt[(k + 3) * 512 + c];
  }
  us[c] = (a0 + a1 + a2 + a3) * cmd_w[c];
  __syncthreads();

  const float* lstmb = lstm + (size_t)b * SEQL * 512;
  {
    int s = c >> 4, u = c & 15;
    float p = 0.f;
    const float* lr = lstmb + s * 512;
    for (int r = u; r < 512; r += 16) p += us[r] * lr[r];
    red[c] = p;
  }
  __syncthreads();
  if (c < 32) {
    float raw = cmd_b[0];
    for (int u = 0; u < 16; u++) raw += red[c * 16 + u];
    raw = (c < q_len[b]) ? raw : -1e30f;
    float mx = raw;
    for (int off = 16; off; off >>= 1) mx = fmaxf(mx, __shfl_xor(mx, off, 32));
    float e = expf(raw - mx);
    float sm = e;
    for (int off = 16; off; off >>= 1) sm += __shfl_xor(sm, off, 32);
    atts[c] = e / sm;
  }
  __syncthreads();
  float cd = 0.f;
#pragma unroll
  for (int s = 0; s < 32; s++) cd += atts[s] * lstmb[s * 512 + c];
  cmds[c] = cd;
  __syncthreads();

  float b0 = W_b[c], b1 = 0.f, b2 = 0.f, b3 = 0.f;
#pragma unroll 4
  for (int k = 0; k < 512; k += 4) {
    b0 += cmds[k] * w2T[k * 512 + c];
    b1 += cmds[k + 1] * w2T[(k + 1) * 512 + c];
    b2 += cmds[k + 2] * w2T[(k + 2) * 512 + c];
    b3 += cmds[k + 3] * w2T[(k + 3) * 512 + c];
  }
  bias2[((size_t)(t * 64 + b)) * 512 + c] = b0 + b1 + b2 + b3;
}

// ---------------------------------------------------------------------------
// Direct-B GEMM: C[M,512] = A'[M,K] @ Bw[512,K]^T + bias.
// Tile 64 rows x 512 cols (FULL N): A loaded/stenciled ONCE per row-block.
// 4 waves, each 64x128 output (acc[4][8]). BK=64.
// B is NOT staged: W1/kb_bf are L2-resident, B fragments read directly from
// global per MFMA (short8 @ row*K+k; 16 lanes x 64B lines, hidden under the
// 64-MFMA cluster). LDS holds only A (8 KB, proven XOR swizzle, 0 conflicts).
//   AMODE 0: A' = f32 A, reg-stage + cvt once        (init, K=1024)
//   AMODE 1: A' = 5-point stencil of bf16 X (fused)  (loop, K=512)
// MODE 0: +cbias[col],           no act, out bf16
// MODE 1: +deg(n)*bias2[b][col], elu,    out bf16
// MODE 2: +deg(n)*bias2[b][col], no act, out f32
// ---------------------------------------------------------------------------
template <int AMODE, int MODE, int K>
__global__ __launch_bounds__(256, 2) void dgemm(
    const void* __restrict__ Ap,
    const unsigned short* __restrict__ Bw,
    const float* __restrict__ cbias, const float* __restrict__ bias2,
    void* __restrict__ Cp) {
  __shared__ __align__(128) unsigned short As[64 * 64];  // 8 KB, swizzled

  const int tid = threadIdx.x;
  const int lane = tid & 63;
  const int wn = tid >> 6;          // wave = 128-col slice, 0..3
  const int lr = lane & 15;
  const int lk = lane >> 4;
  const int lr7 = lr & 7;

  // XCD-aware bijective swizzle (grid = 1024, divisible by 8)
  int bid = blockIdx.x;
  int wg = (bid & 7) * (gridDim.x >> 3) + (bid >> 3);
  const size_t rowBase = (size_t)wg * 64;

  floatx4 acc[4][8];
#pragma unroll
  for (int m = 0; m < 4; m++)
#pragma unroll
    for (int n = 0; n < 8; n++) acc[m][n] = {0.f, 0.f, 0.f, 0.f};

  for (int k0 = 0; k0 < K; k0 += 64) {
    __syncthreads();  // safe to overwrite As
    // ---- A stage: 2 granules/thread (64 rows x 8 slots = 512 granules) ----
    if constexpr (AMODE == 0) {
      const float* Af = (const float*)Ap;
#pragma unroll
      for (int j = 0; j < 2; j++) {
        int g = j * 256 + tid;
        int r = g >> 3, u = g & 7;
        const float* src = Af + (rowBase + r) * (size_t)K + k0 + u * 8;
        floatx4 v0 = *(const floatx4*)src;
        floatx4 v1 = *(const floatx4*)(src + 4);
        short8 t;
#pragma unroll
        for (int e = 0; e < 4; e++) {
          t[e] = (short)f2bf(v0[e]);
          t[e + 4] = (short)f2bf(v1[e]);
        }
        *(short8*)((char*)As + r * 128 + ((u ^ (r & 7)) << 4)) = t;
      }
    } else {
      const unsigned short* X = (const unsigned short*)Ap;
#pragma unroll
      for (int j = 0; j < 2; j++) {
        int g = j * 256 + tid;
        int r = g >> 3, u = g & 7;
        size_t R = rowBase + r;
        int n = (int)(R & 1023);
        int gi = n >> 5, gj = n & 31;
        const unsigned short* p = X + R * (size_t)K + k0 + u * 8;
        short8 c = *(const short8*)p;
        float s[8];
#pragma unroll
        for (int e = 0; e < 8; e++) s[e] = bf2f((unsigned short)c[e]);
        if (gi > 0) {
          short8 t = *(const short8*)(p - 32 * 512);
#pragma unroll
          for (int e = 0; e < 8; e++) s[e] += bf2f((unsigned short)t[e]);
        }
        if (gi < 31) {
          short8 t = *(const short8*)(p + 32 * 512);
#pragma unroll
          for (int e = 0; e < 8; e++) s[e] += bf2f((unsigned short)t[e]);
        }
        if (gj > 0) {
          short8 t = *(const short8*)(p - 512);
#pragma unroll
          for (int e = 0; e < 8; e++) s[e] += bf2f((unsigned short)t[e]);
        }
        if (gj < 31) {
          short8 t = *(const short8*)(p + 512);
#pragma unroll
          for (int e = 0; e < 8; e++) s[e] += bf2f((unsigned short)t[e]);
        }
        short8 o;
#pragma unroll
        for (int e = 0; e < 8; e++) o[e] = (short)f2bf(s[e]);
        *(short8*)((char*)As + r * 128 + ((u ^ (r & 7)) << 4)) = o;
      }
    }
    __syncthreads();

    // ---- compute: 2 ksteps x (4 LDS a-reads + 8 global b-reads, 32 MFMA) --
#pragma unroll
    for (int kk = 0; kk < 2; kk++) {
      const int ub = ((kk << 2) + lk) ^ lr7;
      short8 a[4], b[8];
#pragma unroll
      for (int n = 0; n < 8; n++)
        b[n] = *(const short8*)(Bw + (size_t)(wn * 128 + n * 16 + lr) * K +
                                k0 + (kk << 5) + (lk << 3));
#pragma unroll
      for (int m = 0; m < 4; m++)
        a[m] = *(const short8*)((const char*)As + ((m * 16 + lr) << 7) + (ub << 4));
#pragma unroll
      for (int m = 0; m < 4; m++)
#pragma unroll
        for (int n = 0; n < 8; n++)
          acc[m][n] = __builtin_amdgcn_mfma_f32_16x16x32_bf16(a[m], b[n], acc[m][n], 0, 0, 0);
    }
  }

  // Epilogue: C/D layout col=lane&15, row=(lane>>4)*4+reg [m89 verified]
#pragma unroll
  for (int m = 0; m < 4; m++) {
#pragma unroll
    for (int q = 0; q < 4; q++) {
      size_t grow = rowBase + m * 16 + lk * 4 + q;
      float degf = 0.f;
      const float* b2 = nullptr;
      if constexpr (MODE != 0) {
        int nsp = (int)(grow & 1023);
        int ii = nsp >> 5, jj = nsp & 31;
        degf = (float)(1 + (ii > 0) + (ii < 31) + (jj > 0) + (jj < 31));
        b2 = bias2 + (grow >> 10) * CTXD;
      }
#pragma unroll
      for (int n = 0; n < 8; n++) {
        int gcol = wn * 128 + n * 16 + lr;
        float v = acc[m][n][q];
        if constexpr (MODE == 0) v += cbias[gcol];
        else v += degf * b2[gcol];
        if constexpr (MODE == 1) v = elu1(v);
        if constexpr (MODE == 2) ((float*)Cp)[grow * CTXD + gcol] = v;
        else ((unsigned short*)Cp)[grow * CTXD + gcol] = f2bf(v);
      }
    }
  }
}

// ---------------------------------------------------------------------------
extern "C" void kernel_launch(void* const* d_in, const int* in_sizes, int n_in,
                              void* d_out, int out_size, void* d_ws, size_t ws_size,
                              hipStream_t stream) {
  const float* images   = (const float*)d_in[0];
  const float* q_enc    = (const float*)d_in[1];
  const float* lstm     = (const float*)d_in[2];
  const int*   q_len    = (const int*)d_in[3];
  // d_in[4] = adj: implied by the 32x32 grid stencil, not read
  const float* initKB_w = (const float*)d_in[5];
  const float* initKB_b = (const float*)d_in[6];
  const float* W_w      = (const float*)d_in[7];
  const float* W_b      = (const float*)d_in[8];
  const float* qInput_w = (const float*)d_in[9];
  const float* qInput_b = (const float*)d_in[10];
  const float* qT_w     = (const float*)d_in[11];
  const float* qT_b     = (const float*)d_in[12];
  const float* cmd_w    = (const float*)d_in[13];
  const float* cmd_b    = (const float*)d_in[14];

  // ws layout:
  //   X1 (bf16 ping-pong) : 64 MB   (transposed cmd weights aliased at the
  //        front 6 MB — consumed by q1_k/cmdt_k before first dgemm writes X1)
  //   kb_bf / w1_bf / bias2 / q1 after
  char* ws = (char*)d_ws;
  unsigned short* X1    = (unsigned short*)ws;
  float*          qiT   = (float*)ws;                    // 1 MB
  float*          qTT   = (float*)(ws + 1048576);        // 4 MB
  float*          w2T   = (float*)(ws + 5242880);        // 1 MB
  unsigned short* kb_bf = (unsigned short*)(ws + 67108864);
  unsigned short* w1_bf = (unsigned short*)(ws + 68157440);
  float*          bias2 = (float*)(ws + 68681728);
  float*          q1    = (float*)(ws + 69206016);
  unsigned short* X0    = (unsigned short*)d_out;        // bf16 half of d_out

  pack_k<<<9216, 256, 0, stream>>>(initKB_w, W_w, qInput_w, qT_w,
                                   kb_bf, w1_bf, qiT, qTT, w2T);
  q1_k<<<64, 512, 0, stream>>>(q_enc, qiT, qInput_b, q1);
  cmdt_k<<<256, 512, 0, stream>>>(q1, lstm, q_len, qTT, qT_b, cmd_w, cmd_b,
                                  w2T, W_b, bias2);

  // x_loc(0) = images @ initKB_w^T + initKB_b  -> X0  (A read+cvt ONCE)
  dgemm<0, 0, 1024><<<1024, 256, 0, stream>>>(images, kb_bf,
                                              initKB_b, nullptr, X0);

  // t=0..2: fused stencil+GEMM+elu, X ping-pong (bf16)
  dgemm<1, 1, 512><<<1024, 256, 0, stream>>>(X0, w1_bf,
                                             nullptr, bias2 + 0 * 32768, X1);
  dgemm<1, 1, 512><<<1024, 256, 0, stream>>>(X1, w1_bf,
                                             nullptr, bias2 + 1 * 32768, X0);
  dgemm<1, 1, 512><<<1024, 256, 0, stream>>>(X0, w1_bf,
                                             nullptr, bias2 + 2 * 32768, X1);
  // t=3: reads X1 (ws), writes final f32 d_out — disjoint, no race
  dgemm<1, 2, 512><<<1024, 256, 0, stream>>>(X1, w1_bf,
                                             nullptr, bias2 + 3 * 32768, d_out);
}

// Round 9
// 523.469 us; speedup vs baseline: 1.5120x; 1.5120x over previous
//
#include <hip/hip_runtime.h>
#include <hip/hip_bf16.h>
#include <math.h>

// SpatialGNN: B=64, N=1024 (32x32 grid), D_FEAT=1024, CTX=512, S=32, T=4
#define NB 64
#define NNODES 1024
#define CTXD 512
#define SEQL 32

typedef __attribute__((ext_vector_type(8))) short short8;
typedef __attribute__((ext_vector_type(4))) float floatx4;

__device__ __forceinline__ float bf2f(unsigned short u) {
  union { unsigned int i; float f; } v; v.i = ((unsigned int)u) << 16; return v.f;
}
__device__ __forceinline__ unsigned short f2bf(float f) {
  union { float f; unsigned int i; } v; v.f = f;
  unsigned int r = v.i + 0x7fffu + ((v.i >> 16) & 1u);  // RNE
  return (unsigned short)(r >> 16);
}
__device__ __forceinline__ float elu1(float x) { return x > 0.f ? x : expm1f(x); }

__device__ __forceinline__ void gload16(const void* g, void* l) {
  __builtin_amdgcn_global_load_lds((const __attribute__((address_space(1))) void*)g,
                                   (__attribute__((address_space(3))) void*)l, 16, 0, 0);
}

// ---------------------------------------------------------------------------
// Pack: bf16 GEMM weights + f32 TRANSPOSED cmd-path weights.
// ---------------------------------------------------------------------------
__global__ __launch_bounds__(256) void pack_k(const float* __restrict__ kbw,
                                              const float* __restrict__ Ww,
                                              const float* __restrict__ qiw,
                                              const float* __restrict__ qtw,
                                              unsigned short* __restrict__ kb_bf,
                                              unsigned short* __restrict__ w1_bf,
                                              float* __restrict__ qiT,
                                              float* __restrict__ qTT,
                                              float* __restrict__ w2T) {
  int idx = blockIdx.x * 256 + threadIdx.x;
  if (idx < 524288) {
    kb_bf[idx] = f2bf(kbw[idx]);
  } else if (idx < 786432) {
    int o = idx - 524288;
    w1_bf[o] = f2bf(Ww[(o >> 9) * 1024 + (o & 511)]);
  } else if (idx < 1048576) {
    int o = idx - 786432;
    int k = o >> 9, c = o & 511;
    qiT[o] = qiw[c * 512 + k];
  } else if (idx < 2097152) {
    int o = idx - 1048576;
    int t = o >> 18, r = o & 262143;
    int k = r >> 9, c = r & 511;
    qTT[o] = qtw[((size_t)t * 512 + c) * 512 + k];
  } else {
    int o = idx - 2097152;
    int k = o >> 9, c = o & 511;
    w2T[o] = Ww[c * 1024 + 512 + k];
  }
}

// ---------------------------------------------------------------------------
// q1[b][c] = elu(q_enc[b] @ qInput_w^T + qInput_b)
// ---------------------------------------------------------------------------
__global__ __launch_bounds__(512) void q1_k(const float* __restrict__ q_enc,
                                            const float* __restrict__ qiT,
                                            const float* __restrict__ qInput_b,
                                            float* __restrict__ q1) {
  int b = blockIdx.x, c = threadIdx.x;
  __shared__ float qes[512];
  qes[c] = q_enc[b * 512 + c];
  __syncthreads();
  float a0 = qInput_b[c], a1 = 0.f, a2 = 0.f, a3 = 0.f;
#pragma unroll 4
  for (int k = 0; k < 512; k += 4) {
    a0 += qes[k] * qiT[k * 512 + c];
    a1 += qes[k + 1] * qiT[(k + 1) * 512 + c];
    a2 += qes[k + 2] * qiT[(k + 2) * 512 + c];
    a3 += qes[k + 3] * qiT[(k + 3) * 512 + c];
  }
  q1[b * 512 + c] = elu1(a0 + a1 + a2 + a3);
}

// ---------------------------------------------------------------------------
// Per (t,b): q_cmd -> raw_att -> softmax -> cmd -> bias2[t][b][:]
// ---------------------------------------------------------------------------
__global__ __launch_bounds__(512) void cmdt_k(
    const float* __restrict__ q1, const float* __restrict__ lstm,
    const int* __restrict__ q_len,
    const float* __restrict__ qTT, const float* __restrict__ qT_b,
    const float* __restrict__ cmd_w, const float* __restrict__ cmd_b,
    const float* __restrict__ w2T, const float* __restrict__ W_b,
    float* __restrict__ bias2) {
  int b = blockIdx.x & 63;
  int t = blockIdx.x >> 6;
  int c = threadIdx.x;
  __shared__ float q1s[512];
  __shared__ float us[512];
  __shared__ float red[512];
  __shared__ float atts[32];
  __shared__ float cmds[512];

  q1s[c] = q1[b * 512 + c];
  __syncthreads();

  const float* wt = qTT + (size_t)t * 262144;
  float a0 = qT_b[t * 512 + c], a1 = 0.f, a2 = 0.f, a3 = 0.f;
#pragma unroll 4
  for (int k = 0; k < 512; k += 4) {
    a0 += q1s[k] * wt[k * 512 + c];
    a1 += q1s[k + 1] * wt[(k + 1) * 512 + c];
    a2 += q1s[k + 2] * wt[(k + 2) * 512 + c];
    a3 += q1s[k + 3] * wt[(k + 3) * 512 + c];
  }
  us[c] = (a0 + a1 + a2 + a3) * cmd_w[c];
  __syncthreads();

  const float* lstmb = lstm + (size_t)b * SEQL * 512;
  {
    int s = c >> 4, u = c & 15;
    float p = 0.f;
    const float* lr = lstmb + s * 512;
    for (int r = u; r < 512; r += 16) p += us[r] * lr[r];
    red[c] = p;
  }
  __syncthreads();
  if (c < 32) {
    float raw = cmd_b[0];
    for (int u = 0; u < 16; u++) raw += red[c * 16 + u];
    raw = (c < q_len[b]) ? raw : -1e30f;
    float mx = raw;
    for (int off = 16; off; off >>= 1) mx = fmaxf(mx, __shfl_xor(mx, off, 32));
    float e = expf(raw - mx);
    float sm = e;
    for (int off = 16; off; off >>= 1) sm += __shfl_xor(sm, off, 32);
    atts[c] = e / sm;
  }
  __syncthreads();
  float cd = 0.f;
#pragma unroll
  for (int s = 0; s < 32; s++) cd += atts[s] * lstmb[s * 512 + c];
  cmds[c] = cd;
  __syncthreads();

  float b0 = W_b[c], b1 = 0.f, b2 = 0.f, b3 = 0.f;
#pragma unroll 4
  for (int k = 0; k < 512; k += 4) {
    b0 += cmds[k] * w2T[k * 512 + c];
    b1 += cmds[k + 1] * w2T[(k + 1) * 512 + c];
    b2 += cmds[k + 2] * w2T[(k + 2) * 512 + c];
    b3 += cmds[k + 3] * w2T[(k + 3) * 512 + c];
  }
  bias2[((size_t)(t * 64 + b)) * 512 + c] = b0 + b1 + b2 + b3;
}

// ---------------------------------------------------------------------------
// 5-point stencil: y[b,n,:] = sum_{m in nbr(n)} x[b,m,:]   (bf16, f32 sum)
// ---------------------------------------------------------------------------
__global__ __launch_bounds__(256) void stencil_k(const unsigned short* __restrict__ x,
                                                 unsigned short* __restrict__ y) {
  int g = blockIdx.x * 256 + threadIdx.x;
  int v = g & 63;
  int n = (g >> 6) & 1023;
  int b = g >> 16;
  size_t base = ((((size_t)b << 10) + n) << 9) + v * 8;
  const unsigned short* p = x + base;
  float acc[8];
  short8 s = *(const short8*)p;
#pragma unroll
  for (int j = 0; j < 8; j++) acc[j] = bf2f((unsigned short)s[j]);
  int i = n >> 5, jj = n & 31;
  if (i > 0) {
    short8 t = *(const short8*)(p - 32 * 512);
#pragma unroll
    for (int j = 0; j < 8; j++) acc[j] += bf2f((unsigned short)t[j]);
  }
  if (i < 31) {
    short8 t = *(const short8*)(p + 32 * 512);
#pragma unroll
    for (int j = 0; j < 8; j++) acc[j] += bf2f((unsigned short)t[j]);
  }
  if (jj > 0) {
    short8 t = *(const short8*)(p - 512);
#pragma unroll
    for (int j = 0; j < 8; j++) acc[j] += bf2f((unsigned short)t[j]);
  }
  if (jj < 31) {
    short8 t = *(const short8*)(p + 512);
#pragma unroll
    for (int j = 0; j < 8; j++) acc[j] += bf2f((unsigned short)t[j]);
  }
  short8 o;
#pragma unroll
  for (int j = 0; j < 8; j++) o[j] = (short)f2bf(acc[j]);
  *(short8*)(y + base) = o;
}

// ---------------------------------------------------------------------------
// Init GEMM (round-7 proven tgemm, AMODE0/MODE0 only): 64x256 tile, 4 waves,
// BK=64, A=f32 reg-staged+cvt once, B gload_lds, XOR swizzle.
// ---------------------------------------------------------------------------
__global__ __launch_bounds__(256, 3) void igemm(
    const float* __restrict__ Af,
    const unsigned short* __restrict__ Bw,
    const float* __restrict__ cbias,
    unsigned short* __restrict__ Cp) {
  __shared__ __align__(128) unsigned short As[64 * 64];
  __shared__ __align__(128) unsigned short Bs[256 * 64];

  const int tid = threadIdx.x;
  const int lane = tid & 63;
  const int wn = tid >> 6;
  const int lr = lane & 15;
  const int lk = lane >> 4;
  const int lr7 = lr & 7;

  int bid = blockIdx.x;
  int wg = (bid & 7) * (gridDim.x >> 3) + (bid >> 3);
  const size_t rowBase = (size_t)(wg >> 1) * 64;
  const int colBase = (wg & 1) * 256;

  floatx4 acc[4][4];
#pragma unroll
  for (int m = 0; m < 4; m++)
#pragma unroll
    for (int n = 0; n < 4; n++) acc[m][n] = {0.f, 0.f, 0.f, 0.f};

  for (int k0 = 0; k0 < 1024; k0 += 64) {
    __syncthreads();
#pragma unroll
    for (int j = 0; j < 2; j++) {
      int g = j * 256 + tid;
      int r = g >> 3, u = g & 7;
      const float* src = Af + (rowBase + r) * (size_t)1024 + k0 + u * 8;
      floatx4 v0 = *(const floatx4*)src;
      floatx4 v1 = *(const floatx4*)(src + 4);
      short8 t;
#pragma unroll
      for (int e = 0; e < 4; e++) {
        t[e] = (short)f2bf(v0[e]);
        t[e + 4] = (short)f2bf(v1[e]);
      }
      *(short8*)((char*)As + r * 128 + ((u ^ (r & 7)) << 4)) = t;
    }
#pragma unroll
    for (int j = 0; j < 8; j++) {
      int g = j * 256 + tid;
      int r = g >> 3, u = g & 7;
      gload16(Bw + (size_t)(colBase + r) * 1024 + k0 + ((u ^ (r & 7)) << 3),
              (char*)Bs + g * 16);
    }
    __syncthreads();

#pragma unroll
    for (int kk = 0; kk < 2; kk++) {
      const int ub = ((kk << 2) + lk) ^ lr7;
      short8 a[4], b[4];
#pragma unroll
      for (int m = 0; m < 4; m++)
        a[m] = *(const short8*)((const char*)As + (m * 16 + lr) * 128 + (ub << 4));
#pragma unroll
      for (int n = 0; n < 4; n++)
        b[n] = *(const short8*)((const char*)Bs + (wn * 64 + n * 16 + lr) * 128 + (ub << 4));
#pragma unroll
      for (int m = 0; m < 4; m++)
#pragma unroll
        for (int n = 0; n < 4; n++)
          acc[m][n] = __builtin_amdgcn_mfma_f32_16x16x32_bf16(a[m], b[n], acc[m][n], 0, 0, 0);
    }
  }

#pragma unroll
  for (int m = 0; m < 4; m++) {
#pragma unroll
    for (int q = 0; q < 4; q++) {
      size_t grow = rowBase + m * 16 + lk * 4 + q;
#pragma unroll
      for (int n = 0; n < 4; n++) {
        int gcol = colBase + wn * 64 + n * 16 + lr;
        Cp[grow * CTXD + gcol] = f2bf(acc[m][n][q] + cbias[gcol]);
      }
    }
  }
}

// ---------------------------------------------------------------------------
// Loop GEMM, 8-phase counted-vmcnt schedule (T3+T4+T5 per m201 template):
// 256x256 tile, 8 waves (2M x 4N, wave out 128x64), BK=64, K=512 (NT=8 tiles),
// LDS 128 KB: As/Bs [2 dbuf][2 halves][128x64].  Per K-tile: 4 phases, each
// {ds_read subtile + stage 1 half-tile -> barrier -> lgkmcnt(0) -> setprio(1)
//  16 MFMA setprio(0) -> barrier}.  Stage order per tile t: P1:Ah1[t+1],
// P2:Bh1[t+1], P3:Bh0[t+2], P4:Ah0[t+2]; every slot overwritten >=1 barrier-
// phase after its last read.  vmcnt(4) before P4's end barrier confirms tile
// t+1 (counted: 2 half-tiles = 4 loads still in flight); last tiles drain 0.
// MODE 1: +deg*bias2, elu, bf16 out.  MODE 2: +deg*bias2, no act, f32 out.
// ---------------------------------------------------------------------------
template <int MODE>
__global__ __launch_bounds__(512, 2) void gemm8(
    const unsigned short* __restrict__ Ay,
    const unsigned short* __restrict__ Bw,
    const float* __restrict__ bias2,
    void* __restrict__ Cp) {
  __shared__ __align__(128) unsigned short AsL[2][2][8192];  // 64 KB
  __shared__ __align__(128) unsigned short BsL[2][2][8192];  // 64 KB

  const int tid = threadIdx.x;
  const int lane = tid & 63;
  const int wave = tid >> 6;       // 0..7
  const int wm = wave >> 2;        // 0..1  -> A half = wm
  const int wn = wave & 3;         // 0..3  -> B half = wn>>1
  const int lr = lane & 15;
  const int lk = lane >> 4;
  const int lr7 = lr & 7;
  const int rB0 = (wn & 1) * 64;

  int bid = blockIdx.x;
  int wg = (bid & 7) * (gridDim.x >> 3) + (bid >> 3);   // grid=512, %8==0
  const size_t rowBase = (size_t)(wg >> 1) * 256;
  const int colBase = (wg & 1) * 256;

  floatx4 acc[8][4];
#pragma unroll
  for (int m = 0; m < 8; m++)
#pragma unroll
    for (int n = 0; n < 4; n++) acc[m][n] = {0.f, 0.f, 0.f, 0.f};

  // stage one 128x64 half-tile (2 gload16/thread, linear LDS dst, swizzled src)
  auto stgA = [&](int d, int h, int kt) {
#pragma unroll
    for (int j = 0; j < 2; j++) {
      int g = j * 512 + tid, r = g >> 3, u = g & 7;
      gload16(Ay + (rowBase + h * 128 + r) * (size_t)512 + kt * 64 + ((u ^ (r & 7)) << 3),
              (char*)&AsL[d][h][0] + g * 16);
    }
  };
  auto stgB = [&](int d, int h, int kt) {
#pragma unroll
    for (int j = 0; j < 2; j++) {
      int g = j * 512 + tid, r = g >> 3, u = g & 7;
      gload16(Bw + (size_t)(colBase + h * 128 + r) * 512 + kt * 64 + ((u ^ (r & 7)) << 3),
              (char*)&BsL[d][h][0] + g * 16);
    }
  };

  // prologue, issue order matches steady state:
  // Bh0[0], Ah0[0], Ah1[0], Bh1[0], Bh0[1], Ah0[1]
  stgB(0, 0, 0); stgA(0, 0, 0); stgA(0, 1, 0); stgB(0, 1, 0);
  stgB(1, 0, 1); stgA(1, 0, 1);
  asm volatile("s_waitcnt vmcnt(4)" ::: "memory");  // tile 0 landed
  __builtin_amdgcn_sched_barrier(0);
  __builtin_amdgcn_s_barrier();
  __builtin_amdgcn_sched_barrier(0);

  short8 a[2][4], b[2][4];

  for (int t = 0; t < 8; t++) {
    const int d = t & 1;
    const char* Ah = (const char*)&AsL[d][wm][0];
    const char* Bh = (const char*)&BsL[d][wn >> 1][0];

    // ---- P1: read a(m0-3), b(n0-1); stage Ah1[t+1]; MFMA m0-3 x n0-1 ------
#pragma unroll
    for (int kk = 0; kk < 2; kk++) {
      const int ub = ((kk << 2) + lk) ^ lr7;
#pragma unroll
      for (int m = 0; m < 4; m++)
        a[kk][m] = *(const short8*)(Ah + (m * 16 + lr) * 128 + (ub << 4));
#pragma unroll
      for (int n = 0; n < 2; n++)
        b[kk][n] = *(const short8*)(Bh + (rB0 + n * 16 + lr) * 128 + (ub << 4));
    }
    if (t + 1 < 8) stgA(d ^ 1, 1, t + 1);
    __builtin_amdgcn_sched_barrier(0);
    __builtin_amdgcn_s_barrier();
    asm volatile("s_waitcnt lgkmcnt(0)" ::: "memory");
    __builtin_amdgcn_sched_barrier(0);
    __builtin_amdgcn_s_setprio(1);
#pragma unroll
    for (int kk = 0; kk < 2; kk++)
#pragma unroll
      for (int m = 0; m < 4; m++)
#pragma unroll
        for (int n = 0; n < 2; n++)
          acc[m][n] = __builtin_amdgcn_mfma_f32_16x16x32_bf16(a[kk][m], b[kk][n], acc[m][n], 0, 0, 0);
    __builtin_amdgcn_s_setprio(0);
    __builtin_amdgcn_sched_barrier(0);
    __builtin_amdgcn_s_barrier();
    __builtin_amdgcn_sched_barrier(0);

    // ---- P2: read b(n2-3); stage Bh1[t+1]; MFMA m0-3 x n2-3 ---------------
#pragma unroll
    for (int kk = 0; kk < 2; kk++) {
      const int ub = ((kk << 2) + lk) ^ lr7;
#pragma unroll
      for (int n = 2; n < 4; n++)
        b[kk][n] = *(const short8*)(Bh + (rB0 + n * 16 + lr) * 128 + (ub << 4));
    }
    if (t + 1 < 8) stgB(d ^ 1, 1, t + 1);
    __builtin_amdgcn_sched_barrier(0);
    __builtin_amdgcn_s_barrier();
    asm volatile("s_waitcnt lgkmcnt(0)" ::: "memory");
    __builtin_amdgcn_sched_barrier(0);
    __builtin_amdgcn_s_setprio(1);
#pragma unroll
    for (int kk = 0; kk < 2; kk++)
#pragma unroll
      for (int m = 0; m < 4; m++)
#pragma unroll
        for (int n = 2; n < 4; n++)
          acc[m][n] = __builtin_amdgcn_mfma_f32_16x16x32_bf16(a[kk][m], b[kk][n], acc[m][n], 0, 0, 0);
    __builtin_amdgcn_s_setprio(0);
    __builtin_amdgcn_sched_barrier(0);
    __builtin_amdgcn_s_barrier();
    __builtin_amdgcn_sched_barrier(0);

    // ---- P3: read a(m4-7); stage Bh0[t+2]; MFMA m4-7 x n0-1 ---------------
#pragma unroll
    for (int kk = 0; kk < 2; kk++) {
      const int ub = ((kk << 2) + lk) ^ lr7;
#pragma unroll
      for (int m = 0; m < 4; m++)
        a[kk][m] = *(const short8*)(Ah + (64 + m * 16 + lr) * 128 + (ub << 4));
    }
    if (t + 2 < 8) stgB(d, 0, t + 2);
    __builtin_amdgcn_sched_barrier(0);
    __builtin_amdgcn_s_barrier();
    asm volatile("s_waitcnt lgkmcnt(0)" ::: "memory");
    __builtin_amdgcn_sched_barrier(0);
    __builtin_amdgcn_s_setprio(1);
#pragma unroll
    for (int kk = 0; kk < 2; kk++)
#pragma unroll
      for (int m = 0; m < 4; m++)
#pragma unroll
        for (int n = 0; n < 2; n++)
          acc[m + 4][n] = __builtin_amdgcn_mfma_f32_16x16x32_bf16(a[kk][m], b[kk][n], acc[m + 4][n], 0, 0, 0);
    __builtin_amdgcn_s_setprio(0);
    __builtin_amdgcn_sched_barrier(0);
    __builtin_amdgcn_s_barrier();
    __builtin_amdgcn_sched_barrier(0);

    // ---- P4: stage Ah0[t+2]; MFMA m4-7 x n2-3; vmcnt; barrier -------------
    if (t + 2 < 8) stgA(d, 0, t + 2);
    __builtin_amdgcn_sched_barrier(0);
    __builtin_amdgcn_s_setprio(1);
#pragma unroll
    for (int kk = 0; kk < 2; kk++)
#pragma unroll
      for (int m = 0; m < 4; m++)
#pragma unroll
        for (int n = 2; n < 4; n++)
          acc[m + 4][n] = __builtin_amdgcn_mfma_f32_16x16x32_bf16(a[kk][m], b[kk][n], acc[m + 4][n], 0, 0, 0);
    __builtin_amdgcn_s_setprio(0);
    __builtin_amdgcn_sched_barrier(0);
    if (t + 2 < 8) {
      asm volatile("s_waitcnt vmcnt(4)" ::: "memory");  // tile t+1 landed
    } else {
      asm volatile("s_waitcnt vmcnt(0)" ::: "memory");
    }
    __builtin_amdgcn_sched_barrier(0);
    __builtin_amdgcn_s_barrier();
    __builtin_amdgcn_sched_barrier(0);
  }

  // Epilogue: C/D layout col=lane&15, row=(lane>>4)*4+reg [m89]
#pragma unroll
  for (int m = 0; m < 8; m++) {
#pragma unroll
    for (int q = 0; q < 4; q++) {
      size_t grow = rowBase + wm * 128 + m * 16 + lk * 4 + q;
      int nsp = (int)(grow & 1023);
      int ii = nsp >> 5, jj = nsp & 31;
      float degf = (float)(1 + (ii > 0) + (ii < 31) + (jj > 0) + (jj < 31));
      const float* b2 = bias2 + (grow >> 10) * CTXD;
#pragma unroll
      for (int n = 0; n < 4; n++) {
        int gcol = colBase + wn * 64 + n * 16 + lr;
        float v = acc[m][n][q] + degf * b2[gcol];
        if constexpr (MODE == 1) {
          ((unsigned short*)Cp)[grow * CTXD + gcol] = f2bf(elu1(v));
        } else {
          ((float*)Cp)[grow * CTXD + gcol] = v;
        }
      }
    }
  }
}

// ---------------------------------------------------------------------------
extern "C" void kernel_launch(void* const* d_in, const int* in_sizes, int n_in,
                              void* d_out, int out_size, void* d_ws, size_t ws_size,
                              hipStream_t stream) {
  const float* images   = (const float*)d_in[0];
  const float* q_enc    = (const float*)d_in[1];
  const float* lstm     = (const float*)d_in[2];
  const int*   q_len    = (const int*)d_in[3];
  // d_in[4] = adj: implied by the 32x32 grid stencil, not read
  const float* initKB_w = (const float*)d_in[5];
  const float* initKB_b = (const float*)d_in[6];
  const float* W_w      = (const float*)d_in[7];
  const float* W_b      = (const float*)d_in[8];
  const float* qInput_w = (const float*)d_in[9];
  const float* qInput_b = (const float*)d_in[10];
  const float* qT_w     = (const float*)d_in[11];
  const float* qT_b     = (const float*)d_in[12];
  const float* cmd_w    = (const float*)d_in[13];
  const float* cmd_b    = (const float*)d_in[14];

  // ws layout:
  //   y (bf16 stencil out) : 64 MB  (transposed cmd weights aliased at front
  //        6 MB — consumed by q1_k/cmdt_k before first stencil_k writes y)
  //   kb_bf / w1_bf / bias2 / q1 after
  char* ws = (char*)d_ws;
  unsigned short* y     = (unsigned short*)ws;
  float*          qiT   = (float*)ws;                    // 1 MB
  float*          qTT   = (float*)(ws + 1048576);        // 4 MB
  float*          w2T   = (float*)(ws + 5242880);        // 1 MB
  unsigned short* kb_bf = (unsigned short*)(ws + 67108864);
  unsigned short* w1_bf = (unsigned short*)(ws + 68157440);
  float*          bias2 = (float*)(ws + 68681728);
  float*          q1    = (float*)(ws + 69206016);
  unsigned short* xloc  = (unsigned short*)d_out;        // bf16 half of d_out

  pack_k<<<9216, 256, 0, stream>>>(initKB_w, W_w, qInput_w, qT_w,
                                   kb_bf, w1_bf, qiT, qTT, w2T);
  q1_k<<<64, 512, 0, stream>>>(q_enc, qiT, qInput_b, q1);
  cmdt_k<<<256, 512, 0, stream>>>(q1, lstm, q_len, qTT, qT_b, cmd_w, cmd_b,
                                  w2T, W_b, bias2);

  // x_loc = images @ initKB_w^T + initKB_b  -> xloc (d_out bf16)
  igemm<<<2048, 256, 0, stream>>>(images, kb_bf, initKB_b, xloc);

  for (int t = 0; t < 4; t++) {
    stencil_k<<<16384, 256, 0, stream>>>(xloc, y);
    if (t < 3)
      gemm8<1><<<512, 512, 0, stream>>>(y, w1_bf, bias2 + (size_t)t * 32768, xloc);
    else
      gemm8<2><<<512, 512, 0, stream>>>(y, w1_bf, bias2 + (size_t)t * 32768, d_out);
  }
}